// Round 4
// baseline (130.199 us; speedup 1.0000x reference)
//
#include <hip/hip_runtime.h>
#include <hip/hip_bf16.h>

#define HW 4096
#define CIN 192
#define CMID 96

typedef __attribute__((ext_vector_type(8))) short bf16x8;
typedef __attribute__((ext_vector_type(4))) float f32x4;
typedef __attribute__((ext_vector_type(16))) float f32x16;
typedef __attribute__((ext_vector_type(4))) unsigned int u32x4;

static __device__ __forceinline__ unsigned short f2bf(float f) {
    union { float f; unsigned int u; } v;
    v.f = f;
    unsigned int r = v.u + 0x7fffu + ((v.u >> 16) & 1u);
    return (unsigned short)(r >> 16);
}
static __device__ __forceinline__ float b2f(unsigned short h) {
    union { unsigned int u; float f; } v;
    v.u = ((unsigned int)h) << 16;
    return v.f;
}

static __device__ __forceinline__ void gload16(const void* g, void* l) {
    __builtin_amdgcn_global_load_lds(
        (const __attribute__((address_space(1))) unsigned int*)g,
        (__attribute__((address_space(3))) unsigned int*)l, 16, 0, 0);
}

// (1/64) * log2(e), folded into Q at projection time
#define SCQ (0.015625f * 1.44269504089f)

// ---------------------------------------------------------------------------
// Kernel 0: convert weights to bf16.  wqkvb: [3*96][192], wzb: [192][96]
// ---------------------------------------------------------------------------
__global__ __launch_bounds__(256) void convw_kernel(
    const float* __restrict__ wq, const float* __restrict__ wk,
    const float* __restrict__ wv, const float* __restrict__ wz,
    unsigned short* __restrict__ wqkvb, unsigned short* __restrict__ wzb)
{
    int idx = blockIdx.x * 256 + threadIdx.x;
    if (idx < 3 * CMID * CIN) {
        int m = idx / (CMID * CIN), r = idx % (CMID * CIN);
        const float* w = (m == 0) ? wq : ((m == 1) ? wk : wv);
        wqkvb[idx] = f2bf(w[r]);
    } else if (idx < 3 * CMID * CIN + CIN * CMID) {
        int r = idx - 3 * CMID * CIN;
        wzb[r] = f2bf(wz[r]);
    }
}

// ---------------------------------------------------------------------------
// Kernel 1: Q/K/V projections (bf16 MFMA).  Q pre-scaled by SCQ.
// Q,K out [n][i][96] (ushort4 packed stores); V out [n][96][i].
// ---------------------------------------------------------------------------
__global__ __launch_bounds__(256) void qkv_kernel(
    const float* __restrict__ x, const float* __restrict__ pe,
    const unsigned short* __restrict__ wqkvb,
    const float* __restrict__ bq, const float* __restrict__ bk,
    const float* __restrict__ bv,
    unsigned short* __restrict__ Q, unsigned short* __restrict__ K,
    unsigned short* __restrict__ V)
{
    const int n = blockIdx.y, i0 = blockIdx.x * 64, t = threadIdx.x;
    __shared__ unsigned short xt[64 * 200];

    for (int idx = t; idx < CIN * 64; idx += 256) {
        int c = idx >> 6, il = idx & 63;
        float v = x[((size_t)n * CIN + c) * HW + i0 + il]
                + pe[c * 14400 + blockIdx.x * 120 + il];
        xt[il * 200 + c] = f2bf(v);
    }
    __syncthreads();

    const int w = t >> 6, lane = t & 63, l15 = lane & 15, lg = lane >> 4;
    const int p0 = w * 16;

    bf16x8 af[6];
    #pragma unroll
    for (int f = 0; f < 6; ++f)
        af[f] = *(const bf16x8*)(xt + (p0 + l15) * 200 + f * 32 + lg * 8);

    #pragma unroll
    for (int ct = 0; ct < 18; ++ct) {
        const int m = ct / 6, c6 = ct % 6;
        f32x4 acc = (f32x4){0.f, 0.f, 0.f, 0.f};
        const unsigned short* wrow = wqkvb + (ct * 16 + l15) * CIN + lg * 8;
        #pragma unroll
        for (int f = 0; f < 6; ++f) {
            bf16x8 wf = *(const bf16x8*)(wrow + f * 32);
            if (m < 2)
                acc = __builtin_amdgcn_mfma_f32_16x16x32_bf16(wf, af[f], acc, 0, 0, 0);
            else
                acc = __builtin_amdgcn_mfma_f32_16x16x32_bf16(af[f], wf, acc, 0, 0, 0);
        }
        if (m < 2) {
            f32x4 bv4 = *(const f32x4*)(((m == 0) ? bq : bk) + c6 * 16 + lg * 4);
            ushort4 pk4;
            if (m == 0) {
                pk4.x = f2bf((acc[0] + bv4[0]) * SCQ);
                pk4.y = f2bf((acc[1] + bv4[1]) * SCQ);
                pk4.z = f2bf((acc[2] + bv4[2]) * SCQ);
                pk4.w = f2bf((acc[3] + bv4[3]) * SCQ);
            } else {
                pk4.x = f2bf(acc[0] + bv4[0]);
                pk4.y = f2bf(acc[1] + bv4[1]);
                pk4.z = f2bf(acc[2] + bv4[2]);
                pk4.w = f2bf(acc[3] + bv4[3]);
            }
            unsigned short* dst = ((m == 0) ? Q : K) + (size_t)n * HW * CMID;
            *(ushort4*)(dst + (size_t)(i0 + p0 + l15) * CMID + c6 * 16 + lg * 4) = pk4;
        } else {
            const float bias = bv[c6 * 16 + l15];
            ushort4 pk4;
            pk4.x = f2bf(acc[0] + bias); pk4.y = f2bf(acc[1] + bias);
            pk4.z = f2bf(acc[2] + bias); pk4.w = f2bf(acc[3] + bias);
            *(ushort4*)(V + (size_t)n * CMID * HW + (size_t)(c6 * 16 + l15) * HW
                          + i0 + p0 + lg * 4) = pk4;
        }
    }
}

// ---------------------------------------------------------------------------
// Kernel 2: attention core.  KVBLK=32 for K (V staged in 64-j windows),
// 4-way j-split, grid 1024 = 4 blocks/CU resident, n pinned to XCD.
// In-register softmax (no-max, Q pre-scaled); in-lane row sums.
// ---------------------------------------------------------------------------
__global__ __launch_bounds__(256, 4) void attn_kernel(
    const unsigned short* __restrict__ Q, const unsigned short* __restrict__ K,
    const unsigned short* __restrict__ V,
    unsigned short* __restrict__ zp, float* __restrict__ lp)
{
    const int bid = blockIdx.x;
    const int n  = bid & 7;          // n == XCD: K/V slice L2-resident per XCD
    const int jh = bid >> 8;         // 0..3
    const int bx = (bid >> 3) & 31;  // i-block

    const int t = threadIdx.x, w = t >> 6, lane = t & 63;
    const int l31 = lane & 31, hi = lane >> 5;
    const int ib = bx * 128 + w * 32;

    __shared__ unsigned short Ks[2][32 * 128];  // 8KB per buffer
    __shared__ unsigned short Vs[2][96 * 64];   // 12KB per buffer (64-j window)

    const unsigned short* Qb = Q + (size_t)n * HW * CMID;
    const unsigned short* Kb = K + (size_t)n * HW * CMID;
    const unsigned short* Vb = V + (size_t)n * CMID * HW;

    // Q as B-frag: col = i = l31, k = kc*16 + hi*8 + e
    bf16x8 qf[6];
    #pragma unroll
    for (int kc = 0; kc < 6; ++kc)
        qf[kc] = *(const bf16x8*)(Qb + (size_t)(ib + l31) * CMID + kc * 16 + hi * 8);

    // DMA source offsets, pre-swizzled (involution: granule ^= row&7)
    int ksoff[2], vsoff[3];
    #pragma unroll
    for (int s = 0; s < 2; ++s) {
        int row = 4 * (w * 2 + s) + (lane >> 4);   // 0..31
        ksoff[s] = row * CMID + (((lane & 15) ^ (row & 7)) * 8);
    }
    #pragma unroll
    for (int s = 0; s < 3; ++s) {
        int c = 8 * (w * 3 + s) + (lane >> 3);     // 0..95
        vsoff[s] = c * HW + (((lane & 7) ^ (c & 7)) * 8);
    }

#define STAGE_K(J0, BUF) do {                                                      \
    _Pragma("unroll") for (int s = 0; s < 2; ++s)                                  \
        gload16(Kb + (size_t)(J0) * CMID + ksoff[s], &Ks[BUF][(w * 2 + s) * 512]); \
} while (0)
#define STAGE_V(J0, BUF) do {                                                      \
    _Pragma("unroll") for (int s = 0; s < 3; ++s)                                  \
        gload16(Vb + (size_t)(J0) + vsoff[s], &Vs[BUF][(w * 3 + s) * 512]);        \
} while (0)

    const int j00 = jh * 1024;
    STAGE_K(j00, 0);
    STAGE_V(j00, 0);

    f32x16 O[3];
    #pragma unroll
    for (int e = 0; e < 16; ++e) { O[0][e] = 0.f; O[1][e] = 0.f; O[2][e] = 0.f; }
    float lsum = 0.f;

    __syncthreads();

    for (int tt = 0; tt < 32; ++tt) {
        if (tt < 31) STAGE_K(j00 + (tt + 1) * 32, (tt + 1) & 1);
        if ((tt & 1) == 0 && tt < 30)
            STAGE_V(j00 + ((tt >> 1) + 1) * 64, ((tt >> 1) + 1) & 1);

        const unsigned short* Kc = Ks[tt & 1];
        const unsigned short* Vc = Vs[(tt >> 1) & 1];
        const int vhalf = tt & 1;

        // ---- S^T = mfma(A=K rows j, B=Q cols i): D[j][i]
        f32x16 sacc;
        #pragma unroll
        for (int e = 0; e < 16; ++e) sacc[e] = 0.f;
        __builtin_amdgcn_s_setprio(1);
        #pragma unroll
        for (int kc = 0; kc < 6; ++kc) {
            bf16x8 kf = *(const bf16x8*)(Kc + l31 * 128
                                           + ((((kc * 2 + hi) ^ (l31 & 7))) << 3));
            sacc = __builtin_amdgcn_mfma_f32_32x32x16_bf16(kf, qf[kc], sacc, 0, 0, 0);
        }
        __builtin_amdgcn_s_setprio(0);

        // ---- P = exp2(S); in-lane row-sum; pack pairs to bf16
        unsigned pkk[4][2];
        #pragma unroll
        for (int q = 0; q < 4; ++q)
            #pragma unroll
            for (int rp = 0; rp < 2; ++rp) {
                float lo = exp2f(sacc[q * 4 + 2 * rp]);
                float hh = exp2f(sacc[q * 4 + 2 * rp + 1]);
                lsum += lo + hh;
                unsigned d;
                asm("v_cvt_pk_bf16_f32 %0, %1, %2" : "=v"(d) : "v"(lo), "v"(hh));
                pkk[q][rp] = d;
            }

        // ---- redistribute to PV A-frags (exchange across lane+-32 halves)
        u32x4 pfu[2];
        #pragma unroll
        for (int p = 0; p < 2; ++p)
            #pragma unroll
            for (int rp = 0; rp < 2; ++rp) {
                unsigned A = pkk[2 * p][rp], B = pkk[2 * p + 1][rp];
                unsigned Ax = (unsigned)__shfl_xor((int)A, 32, 64);
                unsigned Bx = (unsigned)__shfl_xor((int)B, 32, 64);
                pfu[p][rp]     = hi ? Bx : A;
                pfu[p][2 + rp] = hi ? B  : Ax;
            }

        // ---- O += P V
        __builtin_amdgcn_s_setprio(1);
        #pragma unroll
        for (int jc = 0; jc < 2; ++jc) {
            bf16x8 pfv = __builtin_bit_cast(bf16x8, pfu[jc]);
            #pragma unroll
            for (int cc = 0; cc < 3; ++cc) {
                bf16x8 vf = *(const bf16x8*)(Vc + (cc * 32 + l31) * 64
                    + ((((vhalf * 4 + jc * 2 + hi) ^ (l31 & 7))) << 3));
                O[cc] = __builtin_amdgcn_mfma_f32_32x32x16_bf16(pfv, vf, O[cc], 0, 0, 0);
            }
        }
        __builtin_amdgcn_s_setprio(0);

        __syncthreads();
    }
#undef STAGE_K
#undef STAGE_V

    // ---- epilogue: unnormalized O (bf16) + row sums
    unsigned short* zb = zp + ((size_t)jh * 8 + n) * HW * CMID;
    #pragma unroll
    for (int cc = 0; cc < 3; ++cc)
        #pragma unroll
        for (int r = 0; r < 16; ++r) {
            int i = (r & 3) + 8 * (r >> 2) + 4 * hi;
            zb[(size_t)(ib + i) * CMID + cc * 32 + l31] = f2bf(O[cc][r]);
        }

    lsum += __shfl_xor(lsum, 32, 64);
    if (hi == 0) {
        float* lb = lp + ((size_t)jh * 8 + n) * HW;
        lb[ib + l31] = lsum;
    }
}

// ---------------------------------------------------------------------------
// Kernel 3: combine 4 j-slices, normalize, project back (MFMA), add residual.
// ---------------------------------------------------------------------------
__global__ __launch_bounds__(256) void zproj_kernel(
    const unsigned short* __restrict__ zp, const float* __restrict__ lp,
    const unsigned short* __restrict__ wzb, const float* __restrict__ bz,
    const float* __restrict__ x, const float* __restrict__ pe,
    float* __restrict__ out)
{
    const int n = blockIdx.y, i0 = blockIdx.x * 64, t = threadIdx.x;
    __shared__ unsigned short zt[64 * 104];
    __shared__ float ll[64];

    if (t < 64) {
        float s = 0.f;
        #pragma unroll
        for (int sl = 0; sl < 4; ++sl)
            s += lp[(size_t)sl * 8 * HW + (size_t)n * HW + i0 + t];
        ll[t] = 1.f / s;
    }
    __syncthreads();

    for (int idx = t; idx < 64 * 24; idx += 256) {
        int i = idx / 24, c4 = (idx % 24) * 4;
        size_t gidx = ((size_t)n * HW + i0 + i) * CMID + c4;
        float a0 = 0.f, a1 = 0.f, a2 = 0.f, a3 = 0.f;
        #pragma unroll
        for (int sl = 0; sl < 4; ++sl) {
            ushort4 a = *(const ushort4*)(zp + (size_t)sl * 8 * HW * CMID + gidx);
            a0 += b2f(a.x); a1 += b2f(a.y); a2 += b2f(a.z); a3 += b2f(a.w);
        }
        float li = ll[i];
        zt[i * 104 + c4 + 0] = f2bf(a0 * li);
        zt[i * 104 + c4 + 1] = f2bf(a1 * li);
        zt[i * 104 + c4 + 2] = f2bf(a2 * li);
        zt[i * 104 + c4 + 3] = f2bf(a3 * li);
    }
    __syncthreads();

    const int w = t >> 6, lane = t & 63, l15 = lane & 15, lg = lane >> 4;
    const int p0 = w * 16;

    bf16x8 af[3];
    #pragma unroll
    for (int f = 0; f < 3; ++f)
        af[f] = *(const bf16x8*)(zt + (p0 + l15) * 104 + f * 32 + lg * 8);

    #pragma unroll
    for (int ct = 0; ct < 12; ++ct) {
        f32x4 acc = (f32x4){0.f, 0.f, 0.f, 0.f};
        const unsigned short* wrow = wzb + (ct * 16 + l15) * CMID + lg * 8;
        #pragma unroll
        for (int f = 0; f < 3; ++f) {
            bf16x8 wf = *(const bf16x8*)(wrow + f * 32);
            acc = __builtin_amdgcn_mfma_f32_16x16x32_bf16(af[f], wf, acc, 0, 0, 0);
        }
        const int co = ct * 16 + l15;
        const int ibase = i0 + p0 + lg * 4;
        size_t xa = ((size_t)n * CIN + co) * HW + ibase;
        f32x4 xv = *(const f32x4*)(x + xa);
        f32x4 pv = *(const f32x4*)(pe + co * 14400 + blockIdx.x * 120 + p0 + lg * 4);
        const float bias = bz[co];
        f32x4 o;
        #pragma unroll
        for (int r = 0; r < 4; ++r) o[r] = xv[r] + pv[r] + acc[r] + bias;
        *(f32x4*)(out + xa) = o;
    }
}

// ---------------------------------------------------------------------------
extern "C" void kernel_launch(void* const* d_in, const int* in_sizes, int n_in,
                              void* d_out, int out_size, void* d_ws, size_t ws_size,
                              hipStream_t stream) {
    const float* x  = (const float*)d_in[0];
    const float* pe = (const float*)d_in[1];
    const float* wq = (const float*)d_in[2];
    const float* bq = (const float*)d_in[3];
    const float* wk = (const float*)d_in[4];
    const float* bk = (const float*)d_in[5];
    const float* wv = (const float*)d_in[6];
    const float* bv = (const float*)d_in[7];
    const float* wz = (const float*)d_in[8];
    const float* bz = (const float*)d_in[9];
    float* out = (float*)d_out;

    char* ws = (char*)d_ws;
    // ws layout (bytes):
    //        0: wqkvb bf16 [288][192]          110,592 (pad 131072)
    //   131072: wzb   bf16 [192][96]            36,864 (pad 65536)
    //   196608: Q bf16 [8][4096][96]          6,291,456
    //  6488064: K bf16                        6,291,456
    // 12779520: V^T bf16 [8][96][4096]        6,291,456
    // 19070976: zp bf16 [4][8][4096][96]     25,165,824
    // 44236800: lp f32 [4][8][4096]             524,288   (end 44,761,088)
    unsigned short* wqkvb = (unsigned short*)(ws);
    unsigned short* wzb   = (unsigned short*)(ws + 131072);
    unsigned short* Qb    = (unsigned short*)(ws + 196608);
    unsigned short* Kb    = (unsigned short*)(ws + 6488064);
    unsigned short* Vb    = (unsigned short*)(ws + 12779520);
    unsigned short* zpb   = (unsigned short*)(ws + 19070976);
    float*          lpb   = (float*)(ws + 44236800);

    convw_kernel<<<288, 256, 0, stream>>>(wq, wk, wv, wz, wqkvb, wzb);
    qkv_kernel<<<dim3(64, 8), 256, 0, stream>>>(x, pe, wqkvb, bq, bk, bv,
                                                Qb, Kb, Vb);
    attn_kernel<<<1024, 256, 0, stream>>>(Qb, Kb, Vb, zpb, lpb);
    zproj_kernel<<<dim3(64, 8), 256, 0, stream>>>(zpb, lpb, wzb, bz, x, pe, out);
}

// Round 5
// 124.647 us; speedup vs baseline: 1.0445x; 1.0445x over previous
//
#include <hip/hip_runtime.h>
#include <hip/hip_bf16.h>

#define HW 4096
#define CIN 192
#define CMID 96

typedef __attribute__((ext_vector_type(8))) short bf16x8;
typedef __attribute__((ext_vector_type(4))) float f32x4;
typedef __attribute__((ext_vector_type(16))) float f32x16;
typedef __attribute__((ext_vector_type(4))) unsigned int u32x4;

static __device__ __forceinline__ unsigned short f2bf(float f) {
    union { float f; unsigned int u; } v;
    v.f = f;
    unsigned int r = v.u + 0x7fffu + ((v.u >> 16) & 1u);
    return (unsigned short)(r >> 16);
}
static __device__ __forceinline__ float b2f(unsigned short h) {
    union { unsigned int u; float f; } v;
    v.u = ((unsigned int)h) << 16;
    return v.f;
}

static __device__ __forceinline__ void gload16(const void* g, void* l) {
    __builtin_amdgcn_global_load_lds(
        (const __attribute__((address_space(1))) unsigned int*)g,
        (__attribute__((address_space(3))) unsigned int*)l, 16, 0, 0);
}

// (1/64) * log2(e), folded into Q at projection time
#define SCQ (0.015625f * 1.44269504089f)

// ---------------------------------------------------------------------------
// Kernel 0: convert weights to bf16.
// ---------------------------------------------------------------------------
__global__ __launch_bounds__(256) void convw_kernel(
    const float* __restrict__ wq, const float* __restrict__ wk,
    const float* __restrict__ wv, const float* __restrict__ wz,
    unsigned short* __restrict__ wqkvb, unsigned short* __restrict__ wzb)
{
    int idx = blockIdx.x * 256 + threadIdx.x;
    if (idx < 3 * CMID * CIN) {
        int m = idx / (CMID * CIN), r = idx % (CMID * CIN);
        const float* w = (m == 0) ? wq : ((m == 1) ? wk : wv);
        wqkvb[idx] = f2bf(w[r]);
    } else if (idx < 3 * CMID * CIN + CIN * CMID) {
        int r = idx - 3 * CMID * CIN;
        wzb[r] = f2bf(wz[r]);
    }
}

// ---------------------------------------------------------------------------
// Kernel 1: Q/K/V projections (bf16 MFMA).  Q pre-scaled by SCQ.
// Q,K out [n][i][96]; V out [n][96][i]  (V^T).
// ---------------------------------------------------------------------------
__global__ __launch_bounds__(256) void qkv_kernel(
    const float* __restrict__ x, const float* __restrict__ pe,
    const unsigned short* __restrict__ wqkvb,
    const float* __restrict__ bq, const float* __restrict__ bk,
    const float* __restrict__ bv,
    unsigned short* __restrict__ Q, unsigned short* __restrict__ K,
    unsigned short* __restrict__ V)
{
    const int n = blockIdx.y, i0 = blockIdx.x * 64, t = threadIdx.x;
    __shared__ unsigned short xt[64 * 200];

    for (int idx = t; idx < CIN * 64; idx += 256) {
        int c = idx >> 6, il = idx & 63;
        float v = x[((size_t)n * CIN + c) * HW + i0 + il]
                + pe[c * 14400 + blockIdx.x * 120 + il];
        xt[il * 200 + c] = f2bf(v);
    }
    __syncthreads();

    const int w = t >> 6, lane = t & 63, l15 = lane & 15, lg = lane >> 4;
    const int p0 = w * 16;

    bf16x8 af[6];
    #pragma unroll
    for (int f = 0; f < 6; ++f)
        af[f] = *(const bf16x8*)(xt + (p0 + l15) * 200 + f * 32 + lg * 8);

    #pragma unroll
    for (int ct = 0; ct < 18; ++ct) {
        const int m = ct / 6, c6 = ct % 6;
        f32x4 acc = (f32x4){0.f, 0.f, 0.f, 0.f};
        const unsigned short* wrow = wqkvb + (ct * 16 + l15) * CIN + lg * 8;
        #pragma unroll
        for (int f = 0; f < 6; ++f) {
            bf16x8 wf = *(const bf16x8*)(wrow + f * 32);
            if (m < 2)
                acc = __builtin_amdgcn_mfma_f32_16x16x32_bf16(wf, af[f], acc, 0, 0, 0);
            else
                acc = __builtin_amdgcn_mfma_f32_16x16x32_bf16(af[f], wf, acc, 0, 0, 0);
        }
        if (m < 2) {
            f32x4 bv4 = *(const f32x4*)(((m == 0) ? bq : bk) + c6 * 16 + lg * 4);
            ushort4 pk4;
            if (m == 0) {
                pk4.x = f2bf((acc[0] + bv4[0]) * SCQ);
                pk4.y = f2bf((acc[1] + bv4[1]) * SCQ);
                pk4.z = f2bf((acc[2] + bv4[2]) * SCQ);
                pk4.w = f2bf((acc[3] + bv4[3]) * SCQ);
            } else {
                pk4.x = f2bf(acc[0] + bv4[0]);
                pk4.y = f2bf(acc[1] + bv4[1]);
                pk4.z = f2bf(acc[2] + bv4[2]);
                pk4.w = f2bf(acc[3] + bv4[3]);
            }
            unsigned short* dst = ((m == 0) ? Q : K) + (size_t)n * HW * CMID;
            *(ushort4*)(dst + (size_t)(i0 + p0 + l15) * CMID + c6 * 16 + lg * 4) = pk4;
        } else {
            const float bias = bv[c6 * 16 + l15];
            ushort4 pk4;
            pk4.x = f2bf(acc[0] + bias); pk4.y = f2bf(acc[1] + bias);
            pk4.z = f2bf(acc[2] + bias); pk4.w = f2bf(acc[3] + bias);
            *(ushort4*)(V + (size_t)n * CMID * HW + (size_t)(c6 * 16 + l15) * HW
                          + i0 + p0 + lg * 4) = pk4;
        }
    }
}

// ---------------------------------------------------------------------------
// Kernel 2: attention core.  64 q-rows/wave (2 i-sets), 32-j K tiles
// (triple-buffered, prefetch 2 ahead), 64-j V windows (double-buffered,
// prefetch 1 window ahead).  Counted vmcnt + raw s_barrier (no vmcnt(0)
// drain in the loop).  In-register softmax; permlane32_swap exchange.
// ---------------------------------------------------------------------------
__global__ __launch_bounds__(256, 2) void attn_kernel(
    const unsigned short* __restrict__ Q, const unsigned short* __restrict__ K,
    const unsigned short* __restrict__ V,
    unsigned short* __restrict__ zp, float* __restrict__ lp)
{
    const int bid = blockIdx.x;           // 512 = 8 n * 16 iblk * 4 js
    const int n    = bid & 7;             // n == XCD: K/V L2-resident per XCD
    const int iblk = (bid >> 3) & 15;
    const int js   = bid >> 7;            // 0..3

    const int t = threadIdx.x, w = t >> 6, lane = t & 63;
    const int l31 = lane & 31, hi = lane >> 5;
    const int ib = iblk * 256 + w * 64;   // first of 64 q-rows for this wave

    __shared__ unsigned short Ks[3][32 * 128];  // 3 x 8 KB
    __shared__ unsigned short Vs[2][96 * 64];   // 2 x 12 KB

    const unsigned short* Qb = Q + (size_t)n * HW * CMID;
    const unsigned short* Kb = K + (size_t)n * HW * CMID;
    const unsigned short* Vb = V + (size_t)n * CMID * HW;

    // Q as B-frag: col = i, k = kc*16 + hi*8 + e
    bf16x8 qf[2][6];
    #pragma unroll
    for (int is = 0; is < 2; ++is)
        #pragma unroll
        for (int kc = 0; kc < 6; ++kc)
            qf[is][kc] = *(const bf16x8*)(Qb + (size_t)(ib + is * 32 + l31) * CMID
                                            + kc * 16 + hi * 8);

    // staging source offsets, pre-swizzled (involution: granule ^= row&7)
    int ksoff[2], vsoff[3];
    #pragma unroll
    for (int s = 0; s < 2; ++s) {
        int row = 8 * w + 4 * s + (lane >> 4);           // 0..31
        ksoff[s] = row * CMID + (((lane & 15) ^ (row & 7)) * 8);
    }
    #pragma unroll
    for (int s = 0; s < 3; ++s) {
        int c = 8 * (w * 3 + s) + (lane >> 3);           // 0..95
        vsoff[s] = c * HW + (((lane & 7) ^ (c & 7)) * 8);
    }

    const int j00 = js * 1024;

#define STAGE_K(TILE, KB) do {                                                 \
    _Pragma("unroll") for (int s = 0; s < 2; ++s)                              \
        gload16(Kb + (size_t)(j00 + (TILE) * 32) * CMID + ksoff[s],            \
                &Ks[KB][(w * 2 + s) * 512]);                                   \
} while (0)
#define STAGE_V(WND, VB) do {                                                  \
    _Pragma("unroll") for (int s = 0; s < 3; ++s)                              \
        gload16(Vb + (size_t)(j00 + (WND) * 64) + vsoff[s],                    \
                &Vs[VB][(w * 3 + s) * 512]);                                   \
} while (0)

    f32x16 O[2][3];
    #pragma unroll
    for (int is = 0; is < 2; ++is)
        #pragma unroll
        for (int cc = 0; cc < 3; ++cc)
            #pragma unroll
            for (int e = 0; e < 16; ++e) O[is][cc][e] = 0.f;
    float lsum0 = 0.f, lsum1 = 0.f;

    STAGE_K(0, 0);
    STAGE_K(1, 1);
    STAGE_V(0, 0);
    asm volatile("s_waitcnt vmcnt(0)" ::: "memory");
    __builtin_amdgcn_s_barrier();

#define BODY(KBUF, VBUF, VHALF) do {                                           \
    const unsigned short* Kc = &Ks[KBUF][0];                                   \
    const unsigned short* Vc = &Vs[VBUF][0];                                   \
    f32x16 s0, s1;                                                             \
    _Pragma("unroll") for (int e = 0; e < 16; ++e) { s0[e] = 0.f; s1[e] = 0.f; } \
    __builtin_amdgcn_s_setprio(1);                                             \
    _Pragma("unroll") for (int kc = 0; kc < 6; ++kc) {                         \
        bf16x8 kf = *(const bf16x8*)(Kc + l31 * 128 +                          \
                      (((kc * 2 + hi) ^ (l31 & 7)) << 3));                     \
        s0 = __builtin_amdgcn_mfma_f32_32x32x16_bf16(kf, qf[0][kc], s0, 0, 0, 0); \
        s1 = __builtin_amdgcn_mfma_f32_32x32x16_bf16(kf, qf[1][kc], s1, 0, 0, 0); \
    }                                                                          \
    __builtin_amdgcn_s_setprio(0);                                             \
    unsigned pkk[2][4][2];                                                     \
    _Pragma("unroll") for (int q = 0; q < 4; ++q)                              \
        _Pragma("unroll") for (int rp = 0; rp < 2; ++rp) {                     \
            float lo0 = __builtin_exp2f(s0[q * 4 + 2 * rp]);                   \
            float hh0 = __builtin_exp2f(s0[q * 4 + 2 * rp + 1]);               \
            float lo1 = __builtin_exp2f(s1[q * 4 + 2 * rp]);                   \
            float hh1 = __builtin_exp2f(s1[q * 4 + 2 * rp + 1]);               \
            lsum0 += lo0 + hh0; lsum1 += lo1 + hh1;                            \
            asm("v_cvt_pk_bf16_f32 %0, %1, %2"                                 \
                : "=v"(pkk[0][q][rp]) : "v"(lo0), "v"(hh0));                   \
            asm("v_cvt_pk_bf16_f32 %0, %1, %2"                                 \
                : "=v"(pkk[1][q][rp]) : "v"(lo1), "v"(hh1));                   \
        }                                                                      \
    u32x4 pfu[2][2];                                                           \
    _Pragma("unroll") for (int is = 0; is < 2; ++is)                           \
        _Pragma("unroll") for (int jc = 0; jc < 2; ++jc) {                     \
            unsigned x0 = pkk[is][2 * jc][0], y0 = pkk[is][2 * jc + 1][0];     \
            unsigned x1 = pkk[is][2 * jc][1], y1 = pkk[is][2 * jc + 1][1];     \
            asm("v_permlane32_swap_b32 %0, %1" : "+v"(y0), "+v"(x0));          \
            asm("v_permlane32_swap_b32 %0, %1" : "+v"(y1), "+v"(x1));          \
            pfu[is][jc][0] = x0; pfu[is][jc][1] = x1;                          \
            pfu[is][jc][2] = y0; pfu[is][jc][3] = y1;                          \
        }                                                                      \
    __builtin_amdgcn_s_setprio(1);                                             \
    _Pragma("unroll") for (int jc = 0; jc < 2; ++jc) {                         \
        bf16x8 pa0 = __builtin_bit_cast(bf16x8, pfu[0][jc]);                   \
        bf16x8 pa1 = __builtin_bit_cast(bf16x8, pfu[1][jc]);                   \
        _Pragma("unroll") for (int cc = 0; cc < 3; ++cc) {                     \
            bf16x8 vf = *(const bf16x8*)(Vc + (cc * 32 + l31) * 64 +           \
                          ((((VHALF) * 4 + jc * 2 + hi) ^ (l31 & 7)) << 3));   \
            O[0][cc] = __builtin_amdgcn_mfma_f32_32x32x16_bf16(pa0, vf, O[0][cc], 0, 0, 0); \
            O[1][cc] = __builtin_amdgcn_mfma_f32_32x32x16_bf16(pa1, vf, O[1][cc], 0, 0, 0); \
        }                                                                      \
    }                                                                          \
    __builtin_amdgcn_s_setprio(0);                                             \
} while (0)

    int kb = 0, kb1 = 1, kb2 = 2;
    for (int tt = 0; tt < 32; tt += 2) {
        // ---- even sub-iter: tile tt, window tt/2, half 0
        {
            const int pfk = (tt + 2 < 32) ? tt + 2 : 31;
            STAGE_K(pfk, kb2);
            const int wn = (tt >> 1) + 1;
            const int pfw = (wn < 16) ? wn : 15;
            STAGE_V(pfw, wn & 1);
            BODY(kb, (tt >> 1) & 1, 0);
            asm volatile("s_waitcnt vmcnt(5)" ::: "memory");
            __builtin_amdgcn_s_barrier();
        }
        // ---- odd sub-iter: tile tt+1, window tt/2, half 1
        {
            const int pfk = (tt + 3 < 32) ? tt + 3 : 31;
            STAGE_K(pfk, kb);
            BODY(kb1, (tt >> 1) & 1, 1);
            asm volatile("s_waitcnt vmcnt(2)" ::: "memory");
            __builtin_amdgcn_s_barrier();
        }
        const int tmp = kb;
        kb = kb2; kb2 = kb1; kb1 = tmp;
    }
#undef BODY
#undef STAGE_K
#undef STAGE_V

    asm volatile("s_waitcnt vmcnt(0)" ::: "memory");

    // ---- epilogue: unnormalized O (bf16) + row sums
    unsigned short* zb = zp + ((size_t)js * 8 + n) * HW * CMID;
    #pragma unroll
    for (int is = 0; is < 2; ++is)
        #pragma unroll
        for (int cc = 0; cc < 3; ++cc)
            #pragma unroll
            for (int r = 0; r < 16; ++r) {
                int i = ib + is * 32 + (r & 3) + 8 * (r >> 2) + 4 * hi;
                zb[(size_t)i * CMID + cc * 32 + l31] = f2bf(O[is][cc][r]);
            }

    lsum0 += __shfl_xor(lsum0, 32, 64);
    lsum1 += __shfl_xor(lsum1, 32, 64);
    if (hi == 0) {
        float* lb = lp + ((size_t)js * 8 + n) * HW;
        lb[ib + l31]      = lsum0;
        lb[ib + 32 + l31] = lsum1;
    }
}

// ---------------------------------------------------------------------------
// Kernel 3: combine 4 j-slices, normalize, project back (MFMA), add residual.
// ---------------------------------------------------------------------------
__global__ __launch_bounds__(256) void zproj_kernel(
    const unsigned short* __restrict__ zp, const float* __restrict__ lp,
    const unsigned short* __restrict__ wzb, const float* __restrict__ bz,
    const float* __restrict__ x, const float* __restrict__ pe,
    float* __restrict__ out)
{
    const int n = blockIdx.y, i0 = blockIdx.x * 64, t = threadIdx.x;
    __shared__ unsigned short zt[64 * 104];
    __shared__ float ll[64];

    if (t < 64) {
        float s = 0.f;
        #pragma unroll
        for (int sl = 0; sl < 4; ++sl)
            s += lp[(size_t)sl * 8 * HW + (size_t)n * HW + i0 + t];
        ll[t] = 1.f / s;
    }
    __syncthreads();

    for (int idx = t; idx < 64 * 24; idx += 256) {
        int i = idx / 24, c4 = (idx % 24) * 4;
        size_t gidx = ((size_t)n * HW + i0 + i) * CMID + c4;
        float a0 = 0.f, a1 = 0.f, a2 = 0.f, a3 = 0.f;
        #pragma unroll
        for (int sl = 0; sl < 4; ++sl) {
            ushort4 a = *(const ushort4*)(zp + (size_t)sl * 8 * HW * CMID + gidx);
            a0 += b2f(a.x); a1 += b2f(a.y); a2 += b2f(a.z); a3 += b2f(a.w);
        }
        float li = ll[i];
        zt[i * 104 + c4 + 0] = f2bf(a0 * li);
        zt[i * 104 + c4 + 1] = f2bf(a1 * li);
        zt[i * 104 + c4 + 2] = f2bf(a2 * li);
        zt[i * 104 + c4 + 3] = f2bf(a3 * li);
    }
    __syncthreads();

    const int w = t >> 6, lane = t & 63, l15 = lane & 15, lg = lane >> 4;
    const int p0 = w * 16;

    bf16x8 af[3];
    #pragma unroll
    for (int f = 0; f < 3; ++f)
        af[f] = *(const bf16x8*)(zt + (p0 + l15) * 104 + f * 32 + lg * 8);

    #pragma unroll
    for (int ct = 0; ct < 12; ++ct) {
        f32x4 acc = (f32x4){0.f, 0.f, 0.f, 0.f};
        const unsigned short* wrow = wzb + (ct * 16 + l15) * CMID + lg * 8;
        #pragma unroll
        for (int f = 0; f < 3; ++f) {
            bf16x8 wf = *(const bf16x8*)(wrow + f * 32);
            acc = __builtin_amdgcn_mfma_f32_16x16x32_bf16(af[f], wf, acc, 0, 0, 0);
        }
        const int co = ct * 16 + l15;
        const int ibase = i0 + p0 + lg * 4;
        size_t xa = ((size_t)n * CIN + co) * HW + ibase;
        f32x4 xv = *(const f32x4*)(x + xa);
        f32x4 pv = *(const f32x4*)(pe + co * 14400 + blockIdx.x * 120 + p0 + lg * 4);
        const float bias = bz[co];
        f32x4 o;
        #pragma unroll
        for (int r = 0; r < 4; ++r) o[r] = xv[r] + pv[r] + acc[r] + bias;
        *(f32x4*)(out + xa) = o;
    }
}

// ---------------------------------------------------------------------------
extern "C" void kernel_launch(void* const* d_in, const int* in_sizes, int n_in,
                              void* d_out, int out_size, void* d_ws, size_t ws_size,
                              hipStream_t stream) {
    const float* x  = (const float*)d_in[0];
    const float* pe = (const float*)d_in[1];
    const float* wq = (const float*)d_in[2];
    const float* bq = (const float*)d_in[3];
    const float* wk = (const float*)d_in[4];
    const float* bk = (const float*)d_in[5];
    const float* wv = (const float*)d_in[6];
    const float* bv = (const float*)d_in[7];
    const float* wz = (const float*)d_in[8];
    const float* bz = (const float*)d_in[9];
    float* out = (float*)d_out;

    char* ws = (char*)d_ws;
    // ws layout (bytes) — identical footprint to R4 (proven):
    //        0: wqkvb bf16 [288][192]          110,592 (pad 131072)
    //   131072: wzb   bf16 [192][96]            36,864 (pad 65536)
    //   196608: Q bf16 [8][4096][96]          6,291,456
    //  6488064: K bf16                        6,291,456
    // 12779520: V^T bf16 [8][96][4096]        6,291,456
    // 19070976: zp bf16 [4][8][4096][96]     25,165,824
    // 44236800: lp f32 [4][8][4096]             524,288   (end 44,761,088)
    unsigned short* wqkvb = (unsigned short*)(ws);
    unsigned short* wzb   = (unsigned short*)(ws + 131072);
    unsigned short* Qb    = (unsigned short*)(ws + 196608);
    unsigned short* Kb    = (unsigned short*)(ws + 6488064);
    unsigned short* Vb    = (unsigned short*)(ws + 12779520);
    unsigned short* zpb   = (unsigned short*)(ws + 19070976);
    float*          lpb   = (float*)(ws + 44236800);

    convw_kernel<<<288, 256, 0, stream>>>(wq, wk, wv, wz, wqkvb, wzb);
    qkv_kernel<<<dim3(64, 8), 256, 0, stream>>>(x, pe, wqkvb, bq, bk, bv,
                                                Qb, Kb, Vb);
    attn_kernel<<<512, 256, 0, stream>>>(Qb, Kb, Vb, zpb, lpb);
    zproj_kernel<<<dim3(64, 8), 256, 0, stream>>>(zpb, lpb, wzb, bz, x, pe, out);
}